// Round 1
// baseline (31108.823 us; speedup 1.0000x reference)
//
#include <hip/hip_runtime.h>
#include <cstdint>
#include <cstddef>

#ifndef __has_builtin
#define __has_builtin(x) 0
#endif

#define TSTEPS 50000
#define DDIM   768
#define GDIM   512   // 4*F gates
#define FDIM   128

typedef _Float16 half2_t __attribute__((ext_vector_type(2)));

__device__ __forceinline__ uint32_t pack2_rn(float a, float b) {
  uint16_t ua = __builtin_bit_cast(uint16_t, (_Float16)a);
  uint16_t ub = __builtin_bit_cast(uint16_t, (_Float16)b);
  return (uint32_t)ua | ((uint32_t)ub << 16);
}

__device__ __forceinline__ float fdot2f(uint32_t a, uint32_t b, float acc) {
#if __has_builtin(__builtin_amdgcn_fdot2)
  return __builtin_amdgcn_fdot2(__builtin_bit_cast(half2_t, a),
                                __builtin_bit_cast(half2_t, b), acc, false);
#else
  half2_t ha = __builtin_bit_cast(half2_t, a);
  half2_t hb = __builtin_bit_cast(half2_t, b);
  return acc + (float)ha[0] * (float)hb[0] + (float)ha[1] * (float)hb[1];
#endif
}

__device__ __forceinline__ float fast_sigmoid(float x) {
  float e = __builtin_amdgcn_exp2f(-1.4426950408889634f * x);
  return __builtin_amdgcn_rcpf(1.0f + e);
}

__device__ __forceinline__ float fast_tanh(float x) {
  // tanh(x) = 1 - 2/(exp2(2x*log2e)+1)
  float e = __builtin_amdgcn_exp2f(2.8853900817779268f * x);
  return fmaf(-2.0f, __builtin_amdgcn_rcpf(e + 1.0f), 1.0f);
}

// ---------------------------------------------------------------------------
// pack Whh2 (512x128 f32) -> (512x64) packed half2
__global__ __launch_bounds__(256) void prep_whh(const float* __restrict__ whh,
                                                uint32_t* __restrict__ whh_pk) {
  int idx = blockIdx.x * 256 + threadIdx.x;
  if (idx >= GDIM * (FDIM / 2)) return;
  int j = idx >> 6, q = idx & 63;
  whh_pk[idx] = pack2_rn(whh[j * FDIM + 2 * q], whh[j * FDIM + 2 * q + 1]);
}

// ---------------------------------------------------------------------------
// pre2 = x @ Wih2^T + (bih2+bhh2)   : (T x 768) @ (768 x 512)
// 64x64 tile, BK=32, 256 threads, 4x4 per thread (ty=M, tx=N)
__device__ __forceinline__ void store_row4(float* p, float a, float b, float c, float d) {
  *(float4*)p = make_float4(a, b, c, d);
}
__device__ __forceinline__ void store_row4(_Float16* p, float a, float b, float c, float d) {
  uint2 v; v.x = pack2_rn(a, b); v.y = pack2_rn(c, d);
  *(uint2*)p = v;
}

template <typename PT>
__global__ __launch_bounds__(256) void pre2_gemm(const float* __restrict__ X,
                                                 const float* __restrict__ Wih,
                                                 const float* __restrict__ bih,
                                                 const float* __restrict__ bhh,
                                                 PT* __restrict__ pre2) {
  __shared__ __align__(16) float As[32][68];  // [k][m], pad for banks, 16B-aligned rows
  __shared__ __align__(16) float Bs[32][68];  // [k][n]
  const int tid = threadIdx.x;
  const int m0 = blockIdx.x * 64;
  const int n0 = blockIdx.y * 64;
  const int lr = tid >> 3;          // 0..31
  const int lk = (tid & 7) * 4;     // 0..28
  const int tx = tid & 15;          // N sub-tile
  const int ty = tid >> 4;          // M sub-tile

  float acc[4][4];
#pragma unroll
  for (int i = 0; i < 4; ++i)
#pragma unroll
    for (int j = 0; j < 4; ++j) acc[i][j] = 0.0f;

  int ar0 = m0 + lr;      if (ar0 > TSTEPS - 1) ar0 = TSTEPS - 1;
  int ar1 = m0 + lr + 32; if (ar1 > TSTEPS - 1) ar1 = TSTEPS - 1;
  const int br0 = n0 + lr, br1 = n0 + lr + 32;

#pragma unroll 1
  for (int k0 = 0; k0 < DDIM; k0 += 32) {
    float4 a0 = *(const float4*)&X[(size_t)ar0 * DDIM + k0 + lk];
    float4 a1 = *(const float4*)&X[(size_t)ar1 * DDIM + k0 + lk];
    float4 b0 = *(const float4*)&Wih[(size_t)br0 * DDIM + k0 + lk];
    float4 b1 = *(const float4*)&Wih[(size_t)br1 * DDIM + k0 + lk];
    __syncthreads();  // previous compute done before overwriting LDS
    As[lk + 0][lr] = a0.x; As[lk + 1][lr] = a0.y; As[lk + 2][lr] = a0.z; As[lk + 3][lr] = a0.w;
    As[lk + 0][lr + 32] = a1.x; As[lk + 1][lr + 32] = a1.y; As[lk + 2][lr + 32] = a1.z; As[lk + 3][lr + 32] = a1.w;
    Bs[lk + 0][lr] = b0.x; Bs[lk + 1][lr] = b0.y; Bs[lk + 2][lr] = b0.z; Bs[lk + 3][lr] = b0.w;
    Bs[lk + 0][lr + 32] = b1.x; Bs[lk + 1][lr + 32] = b1.y; Bs[lk + 2][lr + 32] = b1.z; Bs[lk + 3][lr + 32] = b1.w;
    __syncthreads();
#pragma unroll
    for (int kk = 0; kk < 32; ++kk) {
      float4 av = *(const float4*)&As[kk][ty * 4];
      float4 bv = *(const float4*)&Bs[kk][tx * 4];
      acc[0][0] = fmaf(av.x, bv.x, acc[0][0]); acc[0][1] = fmaf(av.x, bv.y, acc[0][1]);
      acc[0][2] = fmaf(av.x, bv.z, acc[0][2]); acc[0][3] = fmaf(av.x, bv.w, acc[0][3]);
      acc[1][0] = fmaf(av.y, bv.x, acc[1][0]); acc[1][1] = fmaf(av.y, bv.y, acc[1][1]);
      acc[1][2] = fmaf(av.y, bv.z, acc[1][2]); acc[1][3] = fmaf(av.y, bv.w, acc[1][3]);
      acc[2][0] = fmaf(av.z, bv.x, acc[2][0]); acc[2][1] = fmaf(av.z, bv.y, acc[2][1]);
      acc[2][2] = fmaf(av.z, bv.z, acc[2][2]); acc[2][3] = fmaf(av.z, bv.w, acc[2][3]);
      acc[3][0] = fmaf(av.w, bv.x, acc[3][0]); acc[3][1] = fmaf(av.w, bv.y, acc[3][1]);
      acc[3][2] = fmaf(av.w, bv.z, acc[3][2]); acc[3][3] = fmaf(av.w, bv.w, acc[3][3]);
    }
  }

  float bias[4];
#pragma unroll
  for (int j = 0; j < 4; ++j) {
    int n = n0 + tx * 4 + j;
    bias[j] = bih[n] + bhh[n];
  }
#pragma unroll
  for (int i = 0; i < 4; ++i) {
    int m = m0 + ty * 4 + i;
    if (m < TSTEPS) {
      store_row4(&pre2[(size_t)m * GDIM + n0 + tx * 4],
                 acc[i][0] + bias[0], acc[i][1] + bias[1],
                 acc[i][2] + bias[2], acc[i][3] + bias[3]);
    }
  }
}

// ---------------------------------------------------------------------------
// Sequential LSTM scan: 1 block, 256 threads. Thread tid owns gate rows
// {tid, tid+256}; Whh rows live in 128 packed-half2 VGPRs; h lives packed in
// LDS (broadcast ds_read_b128). pre2 register-prefetched 4 steps ahead.
template <typename PT>
__global__ __launch_bounds__(256, 1) void lstm_scan(const PT* __restrict__ pre2,
                                                    const uint32_t* __restrict__ whh_pk,
                                                    const float* __restrict__ h0,
                                                    const float* __restrict__ c0,
                                                    uint32_t* __restrict__ hs2p) {
  const int tid = threadIdx.x;
  uint32_t w[128];
  {
    const uint4* wa = (const uint4*)(whh_pk + (size_t)tid * 64);
    const uint4* wb = (const uint4*)(whh_pk + (size_t)(tid + 256) * 64);
#pragma unroll
    for (int q = 0; q < 16; ++q) {
      *(uint4*)&w[4 * q] = wa[q];
      *(uint4*)&w[64 + 4 * q] = wb[q];
    }
  }
  __shared__ __align__(16) uint32_t hpk[64];  // packed h (128 f16)
  __shared__ float gact[512];                 // activated gates

  float c = 0.0f;
  if (tid < 128) c = c0[tid];
  if (tid < 64) hpk[tid] = pack2_rn(h0[2 * tid], h0[2 * tid + 1]);
  __syncthreads();

  const bool row_b_tanh = (tid < 128);  // rows 256..383 are the g-gate
  float pfa0 = (float)pre2[(size_t)0 * GDIM + tid];
  float pfb0 = (float)pre2[(size_t)0 * GDIM + tid + 256];
  float pfa1 = (float)pre2[(size_t)1 * GDIM + tid];
  float pfb1 = (float)pre2[(size_t)1 * GDIM + tid + 256];
  float pfa2 = (float)pre2[(size_t)2 * GDIM + tid];
  float pfb2 = (float)pre2[(size_t)2 * GDIM + tid + 256];
  float pfa3 = (float)pre2[(size_t)3 * GDIM + tid];
  float pfb3 = (float)pre2[(size_t)3 * GDIM + tid + 256];

  auto step = [&](int t, float& pfa, float& pfb) {
    float a0 = 0.f, a1 = 0.f, b0 = 0.f, b1 = 0.f;
#pragma unroll
    for (int q = 0; q < 16; ++q) {
      uint4 hv = *(const uint4*)&hpk[4 * q];
      a0 = fdot2f(w[4 * q + 0], hv.x, a0);
      a1 = fdot2f(w[4 * q + 1], hv.y, a1);
      a0 = fdot2f(w[4 * q + 2], hv.z, a0);
      a1 = fdot2f(w[4 * q + 3], hv.w, a1);
      b0 = fdot2f(w[64 + 4 * q + 0], hv.x, b0);
      b1 = fdot2f(w[64 + 4 * q + 1], hv.y, b1);
      b0 = fdot2f(w[64 + 4 * q + 2], hv.z, b0);
      b1 = fdot2f(w[64 + 4 * q + 3], hv.w, b1);
    }
    float ga = a0 + a1 + pfa;
    float gb = b0 + b1 + pfb;
    // prefetch step t+4 (buffer over-allocated: rows up to T+7 exist)
    pfa = (float)pre2[(size_t)(t + 4) * GDIM + tid];
    pfb = (float)pre2[(size_t)(t + 4) * GDIM + tid + 256];
    float act_a = fast_sigmoid(ga);                                   // i or f
    float act_b = row_b_tanh ? fast_tanh(gb) : fast_sigmoid(gb);      // g or o
    gact[tid] = act_a;
    gact[tid + 256] = act_b;
    __syncthreads();
    if (tid < 128) {
      float gi = gact[tid];
      float gf = gact[tid + 128];
      float gg = gact[tid + 256];
      float go = gact[tid + 384];
      c = fmaf(gf, c, gi * gg);
      float h = go * fast_tanh(c);
      float hnb = __shfl_down(h, 1);  // partner lane (same wave)
      if ((tid & 1) == 0) {
        uint32_t hp = pack2_rn(h, hnb);
        hpk[tid >> 1] = hp;
        hs2p[(size_t)t * 64 + (tid >> 1)] = hp;
      }
    }
    __syncthreads();
  };

#pragma unroll 1
  for (int t = 0; t < TSTEPS; t += 4) {
    step(t + 0, pfa0, pfb0);
    step(t + 1, pfa1, pfb1);
    step(t + 2, pfa2, pfb2);
    step(t + 3, pfa3, pfb3);
  }
}

// ---------------------------------------------------------------------------
// out = sigmoid(hs2 @ Wfc^T + bfc). 128 threads/block, thread n holds Wfc row
// n packed in 64 VGPRs; 64 rows of t per block via LDS broadcast of h-row.
__global__ __launch_bounds__(128) void fcn_kernel(const uint32_t* __restrict__ hs2p,
                                                  const float* __restrict__ Wfc,
                                                  const float* __restrict__ bfc,
                                                  float* __restrict__ out) {
  const int n = threadIdx.x;
  uint32_t w[64];
  {
    const float4* wr = (const float4*)(Wfc + (size_t)n * FDIM);
#pragma unroll
    for (int q = 0; q < 32; ++q) {
      float4 v = wr[q];
      w[2 * q] = pack2_rn(v.x, v.y);
      w[2 * q + 1] = pack2_rn(v.z, v.w);
    }
  }
  const float bias = bfc[n];
  __shared__ __align__(16) uint32_t hrow[64];
  const int tbase = blockIdx.x * 64;
#pragma unroll 1
  for (int s = 0; s < 64; ++s) {
    const int t = tbase + s;
    if (t >= TSTEPS) break;
    if (n < 64) hrow[n] = hs2p[(size_t)t * 64 + n];
    __syncthreads();
    float a0 = 0.f, a1 = 0.f, a2 = 0.f, a3 = 0.f;
#pragma unroll
    for (int q = 0; q < 16; ++q) {
      uint4 hv = *(const uint4*)&hrow[4 * q];
      a0 = fdot2f(w[4 * q + 0], hv.x, a0);
      a1 = fdot2f(w[4 * q + 1], hv.y, a1);
      a2 = fdot2f(w[4 * q + 2], hv.z, a2);
      a3 = fdot2f(w[4 * q + 3], hv.w, a3);
    }
    out[(size_t)t * FDIM + n] = fast_sigmoid((a0 + a1) + (a2 + a3) + bias);
    __syncthreads();
  }
}

// ---------------------------------------------------------------------------
extern "C" void kernel_launch(void* const* d_in, const int* in_sizes, int n_in,
                              void* d_out, int out_size, void* d_ws, size_t ws_size,
                              hipStream_t stream) {
  const float* x    = (const float*)d_in[0];
  const float* h2   = (const float*)d_in[3];
  const float* c2   = (const float*)d_in[4];
  const float* Wih2 = (const float*)d_in[9];
  const float* Whh2 = (const float*)d_in[10];
  const float* bih2 = (const float*)d_in[11];
  const float* bhh2 = (const float*)d_in[12];
  const float* Wfc  = (const float*)d_in[13];
  const float* bfc  = (const float*)d_in[14];
  float* out = (float*)d_out;

  char* ws = (char*)d_ws;
  const size_t off_whh = 0;
  const size_t sz_whh = (size_t)GDIM * 64 * 4;                 // 128 KiB
  const size_t off_hs = off_whh + sz_whh;
  const size_t sz_hs = (size_t)TSTEPS * 64 * 4;                // 12.8 MB
  const size_t off_pre = off_hs + sz_hs;
  const size_t rows = (size_t)TSTEPS + 8;                      // prefetch slack
  const size_t need_f32 = off_pre + rows * GDIM * 4;
  uint32_t* whh_pk = (uint32_t*)(ws + off_whh);
  uint32_t* hs2p = (uint32_t*)(ws + off_hs);

  const dim3 ggrid((TSTEPS + 63) / 64, GDIM / 64);

  prep_whh<<<(GDIM * (FDIM / 2) + 255) / 256, 256, 0, stream>>>(Whh2, whh_pk);

  if (ws_size >= need_f32) {
    float* pre2 = (float*)(ws + off_pre);
    pre2_gemm<float><<<ggrid, 256, 0, stream>>>(x, Wih2, bih2, bhh2, pre2);
    lstm_scan<float><<<1, 256, 0, stream>>>(pre2, whh_pk, h2, c2, hs2p);
  } else {
    _Float16* pre2 = (_Float16*)(ws + off_pre);
    pre2_gemm<_Float16><<<ggrid, 256, 0, stream>>>(x, Wih2, bih2, bhh2, pre2);
    lstm_scan<_Float16><<<1, 256, 0, stream>>>(pre2, whh_pk, h2, c2, hs2p);
  }

  fcn_kernel<<<(TSTEPS + 63) / 64, 128, 0, stream>>>(hs2p, Wfc, bfc, out);
}

// Round 2
// 30256.723 us; speedup vs baseline: 1.0282x; 1.0282x over previous
//
#include <hip/hip_runtime.h>
#include <cstdint>
#include <cstddef>

#ifndef __has_builtin
#define __has_builtin(x) 0
#endif

#define TSTEPS 50000
#define DDIM   768
#define GDIM   512   // 4*F gates
#define FDIM   128

typedef _Float16 half2_t __attribute__((ext_vector_type(2)));

__device__ __forceinline__ uint32_t pack2_rn(float a, float b) {
  uint16_t ua = __builtin_bit_cast(uint16_t, (_Float16)a);
  uint16_t ub = __builtin_bit_cast(uint16_t, (_Float16)b);
  return (uint32_t)ua | ((uint32_t)ub << 16);
}

__device__ __forceinline__ float fdot2f(uint32_t a, uint32_t b, float acc) {
#if __has_builtin(__builtin_amdgcn_fdot2)
  return __builtin_amdgcn_fdot2(__builtin_bit_cast(half2_t, a),
                                __builtin_bit_cast(half2_t, b), acc, false);
#else
  half2_t ha = __builtin_bit_cast(half2_t, a);
  half2_t hb = __builtin_bit_cast(half2_t, b);
  return acc + (float)ha[0] * (float)hb[0] + (float)ha[1] * (float)hb[1];
#endif
}

__device__ __forceinline__ float fast_sigmoid(float x) {
  float e = __builtin_amdgcn_exp2f(-1.4426950408889634f * x);
  return __builtin_amdgcn_rcpf(1.0f + e);
}

// column permutation of pre2 so the scan reads column tid directly:
// scan thread tid = (j<<2)|q wants gate row q*128+j
__device__ __forceinline__ int rowmap(int c) { return ((c & 3) << 7) | (c >> 2); }

// ---------------------------------------------------------------------------
// pack Whh2 (512x128 f32) -> (512x64) packed half2, original row order
__global__ __launch_bounds__(256) void prep_whh(const float* __restrict__ whh,
                                                uint32_t* __restrict__ whh_pk) {
  int idx = blockIdx.x * 256 + threadIdx.x;
  if (idx >= GDIM * (FDIM / 2)) return;
  int j = idx >> 6, q = idx & 63;
  whh_pk[idx] = pack2_rn(whh[j * FDIM + 2 * q], whh[j * FDIM + 2 * q + 1]);
}

// ---------------------------------------------------------------------------
// pre2[:, c] = x @ Wih2[rowmap(c)] + (bih2+bhh2)[rowmap(c)]
// 64x64 tile, BK=32, 256 threads, 4x4 per thread
__device__ __forceinline__ void store_row4(float* p, float a, float b, float c, float d) {
  *(float4*)p = make_float4(a, b, c, d);
}
__device__ __forceinline__ void store_row4(_Float16* p, float a, float b, float c, float d) {
  uint2 v; v.x = pack2_rn(a, b); v.y = pack2_rn(c, d);
  *(uint2*)p = v;
}

template <typename PT>
__global__ __launch_bounds__(256) void pre2_gemm(const float* __restrict__ X,
                                                 const float* __restrict__ Wih,
                                                 const float* __restrict__ bih,
                                                 const float* __restrict__ bhh,
                                                 PT* __restrict__ pre2) {
  __shared__ __align__(16) float As[32][68];
  __shared__ __align__(16) float Bs[32][68];
  const int tid = threadIdx.x;
  const int m0 = blockIdx.x * 64;
  const int n0 = blockIdx.y * 64;
  const int lr = tid >> 3;
  const int lk = (tid & 7) * 4;
  const int tx = tid & 15;
  const int ty = tid >> 4;

  float acc[4][4];
#pragma unroll
  for (int i = 0; i < 4; ++i)
#pragma unroll
    for (int j = 0; j < 4; ++j) acc[i][j] = 0.0f;

  int ar0 = m0 + lr;      if (ar0 > TSTEPS - 1) ar0 = TSTEPS - 1;
  int ar1 = m0 + lr + 32; if (ar1 > TSTEPS - 1) ar1 = TSTEPS - 1;
  const int br0 = rowmap(n0 + lr), br1 = rowmap(n0 + lr + 32);

#pragma unroll 1
  for (int k0 = 0; k0 < DDIM; k0 += 32) {
    float4 a0 = *(const float4*)&X[(size_t)ar0 * DDIM + k0 + lk];
    float4 a1 = *(const float4*)&X[(size_t)ar1 * DDIM + k0 + lk];
    float4 b0 = *(const float4*)&Wih[(size_t)br0 * DDIM + k0 + lk];
    float4 b1 = *(const float4*)&Wih[(size_t)br1 * DDIM + k0 + lk];
    __syncthreads();
    As[lk + 0][lr] = a0.x; As[lk + 1][lr] = a0.y; As[lk + 2][lr] = a0.z; As[lk + 3][lr] = a0.w;
    As[lk + 0][lr + 32] = a1.x; As[lk + 1][lr + 32] = a1.y; As[lk + 2][lr + 32] = a1.z; As[lk + 3][lr + 32] = a1.w;
    Bs[lk + 0][lr] = b0.x; Bs[lk + 1][lr] = b0.y; Bs[lk + 2][lr] = b0.z; Bs[lk + 3][lr] = b0.w;
    Bs[lk + 0][lr + 32] = b1.x; Bs[lk + 1][lr + 32] = b1.y; Bs[lk + 2][lr + 32] = b1.z; Bs[lk + 3][lr + 32] = b1.w;
    __syncthreads();
#pragma unroll
    for (int kk = 0; kk < 32; ++kk) {
      float4 av = *(const float4*)&As[kk][ty * 4];
      float4 bv = *(const float4*)&Bs[kk][tx * 4];
      acc[0][0] = fmaf(av.x, bv.x, acc[0][0]); acc[0][1] = fmaf(av.x, bv.y, acc[0][1]);
      acc[0][2] = fmaf(av.x, bv.z, acc[0][2]); acc[0][3] = fmaf(av.x, bv.w, acc[0][3]);
      acc[1][0] = fmaf(av.y, bv.x, acc[1][0]); acc[1][1] = fmaf(av.y, bv.y, acc[1][1]);
      acc[1][2] = fmaf(av.y, bv.z, acc[1][2]); acc[1][3] = fmaf(av.y, bv.w, acc[1][3]);
      acc[2][0] = fmaf(av.z, bv.x, acc[2][0]); acc[2][1] = fmaf(av.z, bv.y, acc[2][1]);
      acc[2][2] = fmaf(av.z, bv.z, acc[2][2]); acc[2][3] = fmaf(av.z, bv.w, acc[2][3]);
      acc[3][0] = fmaf(av.w, bv.x, acc[3][0]); acc[3][1] = fmaf(av.w, bv.y, acc[3][1]);
      acc[3][2] = fmaf(av.w, bv.z, acc[3][2]); acc[3][3] = fmaf(av.w, bv.w, acc[3][3]);
    }
  }

  float bias[4];
#pragma unroll
  for (int jj = 0; jj < 4; ++jj) {
    int rn = rowmap(n0 + tx * 4 + jj);
    bias[jj] = bih[rn] + bhh[rn];
  }
#pragma unroll
  for (int i = 0; i < 4; ++i) {
    int m = m0 + ty * 4 + i;
    if (m < TSTEPS) {
      store_row4(&pre2[(size_t)m * GDIM + n0 + tx * 4],
                 acc[i][0] + bias[0], acc[i][1] + bias[1],
                 acc[i][2] + bias[2], acc[i][3] + bias[3]);
    }
  }
}

// ---------------------------------------------------------------------------
// Sequential LSTM scan: 1 block, 512 threads (8 waves, 2/SIMD).
// Thread (j=tid>>2, q=tid&3) owns gate row q*128+j entirely (64 packed-half2
// weight regs). h is packed f16 in double-buffered LDS, broadcast-read.
// Quad exchange of activated gates via shfl_xor(1,2); c in registers.
// ONE barrier per step.
template <typename PT>
__global__ __launch_bounds__(512, 2) void lstm_scan(const PT* __restrict__ pre2,
                                                    const uint32_t* __restrict__ whh_pk,
                                                    const float* __restrict__ h0,
                                                    const float* __restrict__ c0,
                                                    uint32_t* __restrict__ hs2p) {
  const int tid = threadIdx.x;     // 0..511
  const int q = tid & 3;           // gate index
  const int j = tid >> 2;          // output element 0..127
  const int row = (q << 7) | j;    // original gate row

  uint32_t w[64];
  {
    const uint4* wr = (const uint4*)(whh_pk + (size_t)row * 64);
#pragma unroll
    for (int i = 0; i < 16; ++i) *(uint4*)&w[4 * i] = wr[i];
  }

  __shared__ __align__(16) uint32_t hpk[2][64];  // packed h, double-buffered
  float c = c0[j];
  if (tid < 64) hpk[0][tid] = pack2_rn(h0[2 * tid], h0[2 * tid + 1]);
  __syncthreads();

  // activation constants, uniform per thread (gate 2 = tanh, others sigmoid)
  const bool isT = (q == 2);
  const float sc = isT ? 2.8853900817779268f : -1.4426950408889634f;
  const float sa = isT ? -2.0f : 1.0f;
  const float sb = isT ? 1.0f : 0.0f;
  const int qlo = q & 1, qhi = q & 2;

  const PT* pcol = pre2 + tid;     // coalesced: column tid (rowmap'ed in GEMM)
  float pf0 = (float)pcol[(size_t)0 * GDIM];
  float pf1 = (float)pcol[(size_t)1 * GDIM];
  float pf2 = (float)pcol[(size_t)2 * GDIM];
  float pf3 = (float)pcol[(size_t)3 * GDIM];

  auto step = [&](int t, float& pf, const uint32_t* __restrict__ hbr,
                  uint32_t* __restrict__ hbw) {
    float a0 = 0.f, a1 = 0.f, a2 = 0.f, a3 = 0.f;
#pragma unroll
    for (int g = 0; g < 16; ++g) {
      uint4 hv = *(const uint4*)&hbr[4 * g];   // broadcast read
      a0 = fdot2f(w[4 * g + 0], hv.x, a0);
      a1 = fdot2f(w[4 * g + 1], hv.y, a1);
      a2 = fdot2f(w[4 * g + 2], hv.z, a2);
      a3 = fdot2f(w[4 * g + 3], hv.w, a3);
    }
    float gsum = ((a0 + a1) + (a2 + a3)) + pf;
    pf = (float)pcol[(size_t)(t + 4) * GDIM];  // prefetch (buffer has slack rows)
    // own activation
    float e = __builtin_amdgcn_exp2f(sc * gsum);
    float r = __builtin_amdgcn_rcpf(1.0f + e);
    float act = fmaf(sa, r, sb);
    // quad all-gather: x_m = gate (q^m)
    float x1 = __shfl_xor(act, 1);
    float x2 = __shfl_xor(act, 2);
    float x3 = __shfl_xor(x1, 2);
    float A0 = qlo ? x1 : act;   // x_{q&1}
    float A1 = qlo ? x3 : x2;    // x_{2|(q&1)}
    float B0 = qlo ? act : x1;   // x_{(q&1)^1}
    float B1 = qlo ? x2 : x3;    // x_{2|((q&1)^1)}
    float gi = qhi ? A1 : A0;    // x_q
    float gf = qhi ? B1 : B0;    // x_{q^1}
    float gg = qhi ? A0 : A1;    // x_{q^2}
    float go = qhi ? B0 : B1;    // x_{q^3}
    c = fmaf(gf, c, gi * gg);
    float e2 = __builtin_amdgcn_exp2f(2.8853900817779268f * c);
    float r2 = __builtin_amdgcn_rcpf(1.0f + e2);
    float th = fmaf(-2.0f, r2, 1.0f);
    float h = go * th;
    float hp = __shfl_xor(h, 4);               // partner output element
    if ((tid & 7) == 0) {
      uint32_t pk = pack2_rn(h, hp);
      hbw[tid >> 3] = pk;
      hs2p[(size_t)t * 64 + (tid >> 3)] = pk;
    }
    __syncthreads();
  };

#pragma unroll 1
  for (int t = 0; t < TSTEPS; t += 4) {
    step(t + 0, pf0, hpk[0], hpk[1]);
    step(t + 1, pf1, hpk[1], hpk[0]);
    step(t + 2, pf2, hpk[0], hpk[1]);
    step(t + 3, pf3, hpk[1], hpk[0]);
  }
}

// ---------------------------------------------------------------------------
// out = sigmoid(hs2 @ Wfc^T + bfc)
__global__ __launch_bounds__(128) void fcn_kernel(const uint32_t* __restrict__ hs2p,
                                                  const float* __restrict__ Wfc,
                                                  const float* __restrict__ bfc,
                                                  float* __restrict__ out) {
  const int n = threadIdx.x;
  uint32_t w[64];
  {
    const float4* wr = (const float4*)(Wfc + (size_t)n * FDIM);
#pragma unroll
    for (int qq = 0; qq < 32; ++qq) {
      float4 v = wr[qq];
      w[2 * qq] = pack2_rn(v.x, v.y);
      w[2 * qq + 1] = pack2_rn(v.z, v.w);
    }
  }
  const float bias = bfc[n];
  __shared__ __align__(16) uint32_t hrow[64];
  const int tbase = blockIdx.x * 64;
#pragma unroll 1
  for (int s = 0; s < 64; ++s) {
    const int t = tbase + s;
    if (t >= TSTEPS) break;
    if (n < 64) hrow[n] = hs2p[(size_t)t * 64 + n];
    __syncthreads();
    float a0 = 0.f, a1 = 0.f, a2 = 0.f, a3 = 0.f;
#pragma unroll
    for (int qq = 0; qq < 16; ++qq) {
      uint4 hv = *(const uint4*)&hrow[4 * qq];
      a0 = fdot2f(w[4 * qq + 0], hv.x, a0);
      a1 = fdot2f(w[4 * qq + 1], hv.y, a1);
      a2 = fdot2f(w[4 * qq + 2], hv.z, a2);
      a3 = fdot2f(w[4 * qq + 3], hv.w, a3);
    }
    out[(size_t)t * FDIM + n] = fast_sigmoid((a0 + a1) + (a2 + a3) + bias);
    __syncthreads();
  }
}

// ---------------------------------------------------------------------------
extern "C" void kernel_launch(void* const* d_in, const int* in_sizes, int n_in,
                              void* d_out, int out_size, void* d_ws, size_t ws_size,
                              hipStream_t stream) {
  const float* x    = (const float*)d_in[0];
  const float* h2   = (const float*)d_in[3];
  const float* c2   = (const float*)d_in[4];
  const float* Wih2 = (const float*)d_in[9];
  const float* Whh2 = (const float*)d_in[10];
  const float* bih2 = (const float*)d_in[11];
  const float* bhh2 = (const float*)d_in[12];
  const float* Wfc  = (const float*)d_in[13];
  const float* bfc  = (const float*)d_in[14];
  float* out = (float*)d_out;

  char* ws = (char*)d_ws;
  const size_t off_whh = 0;
  const size_t sz_whh = (size_t)GDIM * 64 * 4;                 // 128 KiB
  const size_t off_hs = off_whh + sz_whh;
  const size_t sz_hs = (size_t)TSTEPS * 64 * 4;                // 12.8 MB
  const size_t off_pre = off_hs + sz_hs;
  const size_t rows = (size_t)TSTEPS + 8;                      // prefetch slack
  const size_t need_f32 = off_pre + rows * GDIM * 4;
  uint32_t* whh_pk = (uint32_t*)(ws + off_whh);
  uint32_t* hs2p = (uint32_t*)(ws + off_hs);

  const dim3 ggrid((TSTEPS + 63) / 64, GDIM / 64);

  prep_whh<<<(GDIM * (FDIM / 2) + 255) / 256, 256, 0, stream>>>(Whh2, whh_pk);

  if (ws_size >= need_f32) {
    float* pre2 = (float*)(ws + off_pre);
    pre2_gemm<float><<<ggrid, 256, 0, stream>>>(x, Wih2, bih2, bhh2, pre2);
    lstm_scan<float><<<1, 512, 0, stream>>>(pre2, whh_pk, h2, c2, hs2p);
  } else {
    _Float16* pre2 = (_Float16*)(ws + off_pre);
    pre2_gemm<_Float16><<<ggrid, 256, 0, stream>>>(x, Wih2, bih2, bhh2, pre2);
    lstm_scan<_Float16><<<1, 512, 0, stream>>>(pre2, whh_pk, h2, c2, hs2p);
  }

  fcn_kernel<<<(TSTEPS + 63) / 64, 128, 0, stream>>>(hs2p, Wfc, bfc, out);
}